// Round 16
// baseline (205.604 us; speedup 1.0000x reference)
//
#include <hip/hip_runtime.h>
#include <hip/hip_bf16.h>
#include <stdint.h>

#define B_ 16
#define N_ 512
#define E_ 8192
#define D_ 256
#define NBUCKET (B_ * N_)          // bucket per (batch, dst node) = 8192
#define CAP 64                     // records per bucket (mean 8, 11-sigma safe)

// ---- workspace layout (float offsets). No converted params, no flags. ----
constexpr int OFF_VE  = 16;                       // reduced v_edge (256)
constexpr int OFF_TN  = OFF_VE + D_;
constexpr int OFF_S1P = OFF_TN + B_*N_*D_;        // 4 x NBUCKET single-writer slots
constexpr int OFF_S2P = OFF_S1P + 4*NBUCKET;
constexpr int OFF_SC  = OFF_S2P + 4*NBUCKET;
constexpr int OFF_CNT = OFF_SC + B_*E_;           // 8192 ints
constexpr int OFF_REC = OFF_CNT + NBUCKET;        // int x NBUCKET*CAP (2 MB)

__device__ __forceinline__ float bf2f(uint16_t u) {
    union { uint32_t i; float f; } v; v.i = ((uint32_t)u) << 16; return v.f;
}

__device__ __forceinline__ float loadF(const void* p, int i, int isBF) {
    if (isBF) return __bfloat162float(((const __hip_bfloat16*)p)[i]);
    return ((const float*)p)[i];
}

__device__ __forceinline__ float4 loadF4(const void* p, int i, int isBF) {
    if (isBF) {
        ushort4 v = *(const ushort4*)((const uint16_t*)p + i);
        return make_float4(bf2f(v.x), bf2f(v.y), bf2f(v.z), bf2f(v.w));
    }
    return *(const float4*)((const float*)p + i);
}

// mask layouts: 0=u8/bool, 1=int32, 2=bf16, 3=f32
__device__ __forceinline__ bool readMask(const void* p, int i, int ml) {
    if (ml == 0) return ((const uint8_t*)p)[i] != 0;
    if (ml == 1) return ((const int*)p)[i] != 0;
    if (ml == 2) return (((const uint16_t*)p)[i] & 0x7FFFu) != 0;
    return (((const uint32_t*)p)[i] & 0x7FFFFFFFu) != 0;
}

// Inline dtype/mask-layout detection (pure function of fixed input words;
// wave-uniform broadcast loads, L1/L2-hot after the first wave).
__device__ __forceinline__ void detect(const void* obj, const void* emask,
                                       int& isBF, int& ml) {
    const uint32_t* ow = (const uint32_t*)obj;
    int insane = 0;
    #pragma unroll
    for (int i = 0; i < 32; ++i) {
        uint32_t x = ow[i];
        uint32_t lo = x & 0xFFFFu, hi = x >> 16;
        uint32_t el = (lo >> 7) & 0xFFu, eh = (hi >> 7) & 0xFFu;
        if ((lo & 0x7FFFu) && (el < 107u || el > 147u)) insane++;
        if ((hi & 0x7FFFu) && (eh < 107u || eh > 147u)) insane++;
    }
    isBF = (insane >= 8) ? 0 : 1;
    const uint32_t* ew = (const uint32_t*)emask;
    bool i32ok = true, f32ok = true, bfok = true;
    #pragma unroll
    for (int i = 0; i < 16; ++i) {
        uint32_t x = ew[i];
        if (x > 1u) i32ok = false;
        if (x != 0u && x != 0x3F800000u) f32ok = false;
        uint32_t lo = x & 0xFFFFu, hi = x >> 16;
        if (!((lo == 0u || lo == 0x3F80u) && (hi == 0u || hi == 0x3F80u))) bfok = false;
    }
    ml = i32ok ? 1 : (f32ok ? 3 : (bfok ? 2 : 0));
}

// ---- K1 (grid 513): blocks 0..511: tn = obj @ w_node^T (tiled f32 SGEMM, NT,
//      raw inputs, XCD-aware bm-fastest mapping) + single-writer s1/s2 slots
//      + 16 CNT ints zeroed per block.
//      Block 512: reduced v_edge ONLY — 4 waves x 64 d-steps of coalesced
//      float4 loads (wave-parallel, unrolled), LDS-combined. Runs concurrent
//      with the GEMM blocks, so it hides under them. ----
__global__ __launch_bounds__(256) void k_nodefc(const void* obj, const void* wn,
                                                const void* we, const void* wa,
                                                const void* emask, float* ws) {
    int isBF, ml;
    detect(obj, emask, isBF, ml);
    (void)ml;
    int t = threadIdx.x;
    if (blockIdx.x == 512) {
        // v_edge[k] = sum_d wa3[d] * w_edge[d][k]; wave w covers d in [64w,64w+64)
        __shared__ float vep[4][D_];
        int w = t >> 6, lane = t & 63;
        int d0 = w * 64;
        float4 a = make_float4(0.f, 0.f, 0.f, 0.f);
        #pragma unroll 8
        for (int i = 0; i < 64; ++i) {
            int d = d0 + i;
            float c = loadF(wa, 513 + d, isBF);           // uniform
            float4 v = loadF4(we, d * D_ + lane * 4, isBF); // coalesced 1KB/wave
            a.x += c * v.x; a.y += c * v.y; a.z += c * v.z; a.w += c * v.w;
        }
        *(float4*)&vep[w][lane * 4] = a;
        __syncthreads();
        ws[OFF_VE + t] = vep[0][t] + vep[1][t] + vep[2][t] + vep[3][t];
        return;
    }
    __shared__ float As[32][68];
    __shared__ float Bs[32][68];
    float* tn = ws + OFF_TN;
    // zero bucket counters: 8192 ints / 512 blocks = 16 per block (plain stores)
    if (t < 16) ((int*)ws)[OFF_CNT + blockIdx.x * 16 + t] = 0;
    int tx = t & 15, ty = t >> 4;
    int bm = blockIdx.x & 127, bn = blockIdx.x >> 7;   // bm fastest (XCD locality)
    int row0 = bm * 64, col0 = bn * 64;
    int sr = t >> 2;
    int sk = (t & 3) * 8;
    float acc[4][4] = {};
    for (int kt = 0; kt < 8; ++kt) {
        int k0 = kt * 32;
        __syncthreads();
        float4 a0 = loadF4(obj, (row0 + sr) * D_ + k0 + sk, isBF);
        float4 a1 = loadF4(obj, (row0 + sr) * D_ + k0 + sk + 4, isBF);
        float4 b0 = loadF4(wn, (col0 + sr) * D_ + k0 + sk, isBF);
        float4 b1 = loadF4(wn, (col0 + sr) * D_ + k0 + sk + 4, isBF);
        As[sk+0][sr] = a0.x; As[sk+1][sr] = a0.y; As[sk+2][sr] = a0.z; As[sk+3][sr] = a0.w;
        As[sk+4][sr] = a1.x; As[sk+5][sr] = a1.y; As[sk+6][sr] = a1.z; As[sk+7][sr] = a1.w;
        Bs[sk+0][sr] = b0.x; Bs[sk+1][sr] = b0.y; Bs[sk+2][sr] = b0.z; Bs[sk+3][sr] = b0.w;
        Bs[sk+4][sr] = b1.x; Bs[sk+5][sr] = b1.y; Bs[sk+6][sr] = b1.z; Bs[sk+7][sr] = b1.w;
        __syncthreads();
        #pragma unroll
        for (int k = 0; k < 32; ++k) {
            float4 av = *(const float4*)&As[k][ty * 4];
            float4 bv = *(const float4*)&Bs[k][tx * 4];
            acc[0][0] += av.x * bv.x; acc[0][1] += av.x * bv.y;
            acc[0][2] += av.x * bv.z; acc[0][3] += av.x * bv.w;
            acc[1][0] += av.y * bv.x; acc[1][1] += av.y * bv.y;
            acc[1][2] += av.y * bv.z; acc[1][3] += av.y * bv.w;
            acc[2][0] += av.z * bv.x; acc[2][1] += av.z * bv.y;
            acc[2][2] += av.z * bv.z; acc[2][3] += av.z * bv.w;
            acc[3][0] += av.w * bv.x; acc[3][1] += av.w * bv.y;
            acc[3][2] += av.w * bv.z; acc[3][3] += av.w * bv.w;
        }
    }
    #pragma unroll
    for (int rr = 0; rr < 4; ++rr) {
        float4 o = make_float4(acc[rr][0], acc[rr][1], acc[rr][2], acc[rr][3]);
        *(float4*)&tn[(size_t)(row0 + ty * 4 + rr) * D_ + col0 + tx * 4] = o;
    }
    // s1/s2 partial dots over this block's 64 cols -> single-writer slot [bn][row]
    float w1v[4], w2v[4];
    #pragma unroll
    for (int c = 0; c < 4; ++c) {
        w1v[c] = loadF(wa, col0 + tx * 4 + c, isBF);
        w2v[c] = loadF(wa, D_ + col0 + tx * 4 + c, isBF);
    }
    #pragma unroll
    for (int rr = 0; rr < 4; ++rr) {
        float p1 = acc[rr][0]*w1v[0] + acc[rr][1]*w1v[1] + acc[rr][2]*w1v[2] + acc[rr][3]*w1v[3];
        float p2 = acc[rr][0]*w2v[0] + acc[rr][1]*w2v[1] + acc[rr][2]*w2v[2] + acc[rr][3]*w2v[3];
        #pragma unroll
        for (int o = 1; o < 16; o <<= 1) {
            p1 += __shfl_xor(p1, o);
            p2 += __shfl_xor(p2, o);
        }
        if (tx == 0) {
            ws[OFF_S1P + bn * NBUCKET + row0 + ty * 4 + rr] = p1;
            ws[OFF_S2P + bn * NBUCKET + row0 + ty * 4 + rr] = p2;
        }
    }
}

// ---- K2: edge scores, wave per edge; mask-skip; reduced-VE broadcast read;
//          s1/s2 summed from 4 slots (lane 0, L2-hot); bucket fill. ----
__global__ __launch_bounds__(256) void k_scores(const void* obj, const void* pred,
                                                const int2* rel, const void* emask,
                                                const void* sim, const void* wa,
                                                float* ws) {
    int isBF, ml;
    detect(obj, emask, isBF, ml);
    int gid = blockIdx.x * blockDim.x + threadIdx.x;
    int gw = gid >> 6, lane = gid & 63;
    if (gw >= B_ * E_) return;
    bool m = readMask(emask, gw, ml);      // wave-uniform
    if (!m) {
        if (lane == 0) ws[OFF_SC + gw] = -1e9f;
        return;
    }
    int b = gw >> 13;
    float4 ve4 = *(const float4*)(ws + OFF_VE + lane * 4);   // reduced, L1-hot
    float dot;
    if (isBF) {
        ushort4 v = *(const ushort4*)((const uint16_t*)pred + (size_t)gw * D_ + lane * 4);
        dot = bf2f(v.x)*ve4.x + bf2f(v.y)*ve4.y + bf2f(v.z)*ve4.z + bf2f(v.w)*ve4.w;
    } else {
        float4 v = *(const float4*)((const float*)pred + (size_t)gw * D_ + lane * 4);
        dot = v.x*ve4.x + v.y*ve4.y + v.z*ve4.z + v.w*ve4.w;
    }
    #pragma unroll
    for (int off = 32; off > 0; off >>= 1) dot += __shfl_xor(dot, off);
    if (lane == 0) {
        int2 sd = rel[gw];
        int rx = b * N_ + sd.x, ry = b * N_ + sd.y;
        float s1 = ws[OFF_S1P + rx] + ws[OFF_S1P + NBUCKET + rx]
                 + ws[OFF_S1P + 2*NBUCKET + rx] + ws[OFF_S1P + 3*NBUCKET + rx];
        float s2 = ws[OFF_S2P + ry] + ws[OFF_S2P + NBUCKET + ry]
                 + ws[OFF_S2P + 2*NBUCKET + ry] + ws[OFF_S2P + 3*NBUCKET + ry];
        float s = dot + s1 + s2 + loadF(sim, gw, isBF) * loadF(wa, 512, isBF);
        s = (s > 0.f) ? s : 0.01f * s;                 // leaky_relu
        ws[OFF_SC + gw] = s;
        int slot = atomicAdd((int*)ws + OFF_CNT + ry, 1);
        if (slot < CAP)
            ((int*)ws)[OFF_REC + ry * CAP + slot] = sd.x | ((gw & (E_ - 1)) << 16);
    }
}

// ---- K3: block = 4 nodes of one batch; batch XCD-pinned (b = blk & 15).
//          In-block softmax stats from L2-hot SC, then wave-per-node register
//          accum + node-mask + LayerNorm. Raw gam/bet reads. ----
__global__ __launch_bounds__(256) void k_scatter_ln(const void* obj, const void* emask,
                                                    const void* nmask, const void* gam,
                                                    const void* bet, const float* wsc,
                                                    void* out) {
    __shared__ float red[4];
    const float* ws = wsc;
    int isBF, ml;
    detect(obj, emask, isBF, ml);
    int t = threadIdx.x, w = t >> 6, lane = t & 63;
    int b  = blockIdx.x & 15;              // batch (XCD-pinned)
    int s4 = (blockIdx.x >> 4) * 4;        // first node of this block's group
    int ng = b * N_ + s4 + w;              // (batch,node), 0..8191
    const float* sc = ws + OFF_SC + b * E_;
    // in-block softmax stats over this batch's 8192 scores (32 KB, L2-hot)
    float loc[8][4];
    float mx = -3e38f;
    #pragma unroll
    for (int k = 0; k < 8; ++k) {
        float4 v = *(const float4*)(sc + t * 4 + k * 1024);
        loc[k][0] = v.x; loc[k][1] = v.y; loc[k][2] = v.z; loc[k][3] = v.w;
        mx = fmaxf(mx, fmaxf(fmaxf(v.x, v.y), fmaxf(v.z, v.w)));
    }
    #pragma unroll
    for (int o = 32; o > 0; o >>= 1) mx = fmaxf(mx, __shfl_xor(mx, o));
    if (lane == 0) red[w] = mx;
    __syncthreads();
    float M = fmaxf(fmaxf(red[0], red[1]), fmaxf(red[2], red[3]));
    float sum = 0.f;
    #pragma unroll
    for (int k = 0; k < 8; ++k)
        sum += __expf(loc[k][0] - M) + __expf(loc[k][1] - M)
             + __expf(loc[k][2] - M) + __expf(loc[k][3] - M);
    #pragma unroll
    for (int o = 32; o > 0; o >>= 1) sum += __shfl_xor(sum, o);
    __syncthreads();
    if (lane == 0) red[w] = sum;
    __syncthreads();
    float invS = 1.f / (red[0] + red[1] + red[2] + red[3]);
    // wave-per-node gather/accumulate
    int cnt = ((const int*)ws)[OFF_CNT + ng];
    if (cnt > CAP) cnt = CAP;
    const int* rec = (const int*)ws + OFF_REC + ng * CAP;
    const float* tn = ws + OFF_TN + (size_t)b * N_ * D_;
    float v0 = 0.f, v1 = 0.f, v2 = 0.f, v3 = 0.f;
    for (int i = 0; i < cnt; ++i) {
        int rc = rec[i];
        int src = rc & 0xFFFF;
        float wv = __expf(sc[((unsigned)rc) >> 16] - M) * invS;
        const float* s = tn + (size_t)src * D_;
        v0 += wv * s[lane];
        v1 += wv * s[lane + 64];
        v2 += wv * s[lane + 128];
        v3 += wv * s[lane + 192];
    }
    float mk = readMask(nmask, ng, ml) ? 1.f : 0.f;
    v0 *= mk; v1 *= mk; v2 *= mk; v3 *= mk;
    float s_ = v0 + v1 + v2 + v3;
    float sq = v0*v0 + v1*v1 + v2*v2 + v3*v3;
    #pragma unroll
    for (int o = 32; o > 0; o >>= 1) {
        s_ += __shfl_xor(s_, o);
        sq += __shfl_xor(sq, o);
    }
    float mu  = s_ * (1.f / 256.f);
    float var = fmaxf(sq * (1.f / 256.f) - mu * mu, 0.f);
    float rs  = rsqrtf(var + 1e-5f);
    size_t ro = (size_t)ng * D_;
    float g0 = loadF(gam, lane,       isBF), c0 = loadF(bet, lane,       isBF);
    float g1 = loadF(gam, lane + 64,  isBF), c1 = loadF(bet, lane + 64,  isBF);
    float g2 = loadF(gam, lane + 128, isBF), c2 = loadF(bet, lane + 128, isBF);
    float g3 = loadF(gam, lane + 192, isBF), c3 = loadF(bet, lane + 192, isBF);
    float r0 = (v0 - mu) * rs * g0 + c0;
    float r1 = (v1 - mu) * rs * g1 + c1;
    float r2 = (v2 - mu) * rs * g2 + c2;
    float r3 = (v3 - mu) * rs * g3 + c3;
    if (isBF) {
        __hip_bfloat16* o = (__hip_bfloat16*)out + ro;
        o[lane]       = __float2bfloat16(r0);
        o[lane + 64]  = __float2bfloat16(r1);
        o[lane + 128] = __float2bfloat16(r2);
        o[lane + 192] = __float2bfloat16(r3);
    } else {
        float* o = (float*)out + ro;
        o[lane] = r0; o[lane + 64] = r1; o[lane + 128] = r2; o[lane + 192] = r3;
    }
}

extern "C" void kernel_launch(void* const* d_in, const int* in_sizes, int n_in,
                              void* d_out, int out_size, void* d_ws, size_t ws_size,
                              hipStream_t stream) {
    (void)in_sizes; (void)n_in; (void)out_size; (void)ws_size;
    const void* obj   = d_in[0];
    const void* pred  = d_in[1];
    const int2* rel   = (const int2*)d_in[2];
    const void* sim   = d_in[3];
    const void* nmask = d_in[4];
    const void* emask = d_in[5];
    const void* wn    = d_in[6];
    const void* we    = d_in[7];
    const void* wa    = d_in[8];
    const void* gam   = d_in[9];
    const void* bet   = d_in[10];
    float* ws = (float*)d_ws;

    k_nodefc<<<513, 256, 0, stream>>>(obj, wn, we, wa, emask, ws);
    k_scores<<<(B_ * E_) / 4, 256, 0, stream>>>(obj, pred, rel, emask, sim, wa, ws);
    k_scatter_ln<<<NBUCKET / 4, 256, 0, stream>>>(obj, emask, nmask, gam, bet, ws, d_out);
}

// Round 17
// 83.936 us; speedup vs baseline: 2.4495x; 2.4495x over previous
//
#include <hip/hip_runtime.h>
#include <hip/hip_bf16.h>
#include <stdint.h>

#define B_ 16
#define N_ 512
#define E_ 8192
#define D_ 256
#define NBUCKET (B_ * N_)          // bucket per (batch, dst node) = 8192
#define CAP 64                     // records per bucket (mean 8, 11-sigma safe)

// ---- workspace layout (float offsets); flags live in ws[0..1] as ints ----
constexpr int OFF_VE  = 16;                       // reduced v_edge (256)
constexpr int OFF_TN  = OFF_VE + D_;
constexpr int OFF_S1P = OFF_TN + B_*N_*D_;        // 4 x NBUCKET single-writer slots
constexpr int OFF_S2P = OFF_S1P + 4*NBUCKET;
constexpr int OFF_SC  = OFF_S2P + 4*NBUCKET;
constexpr int OFF_CNT = OFF_SC + B_*E_;           // 8192 ints
constexpr int OFF_REC = OFF_CNT + NBUCKET;        // int x NBUCKET*CAP (2 MB)

__device__ __forceinline__ float bf2f(uint16_t u) {
    union { uint32_t i; float f; } v; v.i = ((uint32_t)u) << 16; return v.f;
}

__device__ __forceinline__ float loadF(const void* p, int i, int isBF) {
    if (isBF) return __bfloat162float(((const __hip_bfloat16*)p)[i]);
    return ((const float*)p)[i];
}

__device__ __forceinline__ float4 loadF4(const void* p, int i, int isBF) {
    if (isBF) {
        ushort4 v = *(const ushort4*)((const uint16_t*)p + i);
        return make_float4(bf2f(v.x), bf2f(v.y), bf2f(v.z), bf2f(v.w));
    }
    return *(const float4*)((const float*)p + i);
}

// mask layouts: 0=u8/bool, 1=int32, 2=bf16, 3=f32
__device__ __forceinline__ bool readMask(const void* p, int i, int ml) {
    if (ml == 0) return ((const uint8_t*)p)[i] != 0;
    if (ml == 1) return ((const int*)p)[i] != 0;
    if (ml == 2) return (((const uint16_t*)p)[i] & 0x7FFFu) != 0;
    return (((const uint32_t*)p)[i] & 0x7FFFFFFFu) != 0;
}

// Inline dtype/mask-layout detection. ONLY used in the low-wave-count k_nodefc
// (513 blocks): per-wave prologue cost in a 131K-wave kernel was ~150 us
// (R13/R16 evidence) — hoist, publish flags, let big kernels read 2 ints.
__device__ __forceinline__ void detect(const void* obj, const void* emask,
                                       int& isBF, int& ml) {
    const uint32_t* ow = (const uint32_t*)obj;
    int insane = 0;
    #pragma unroll
    for (int i = 0; i < 32; ++i) {
        uint32_t x = ow[i];
        uint32_t lo = x & 0xFFFFu, hi = x >> 16;
        uint32_t el = (lo >> 7) & 0xFFu, eh = (hi >> 7) & 0xFFu;
        if ((lo & 0x7FFFu) && (el < 107u || el > 147u)) insane++;
        if ((hi & 0x7FFFu) && (eh < 107u || eh > 147u)) insane++;
    }
    isBF = (insane >= 8) ? 0 : 1;
    const uint32_t* ew = (const uint32_t*)emask;
    bool i32ok = true, f32ok = true, bfok = true;
    #pragma unroll
    for (int i = 0; i < 16; ++i) {
        uint32_t x = ew[i];
        if (x > 1u) i32ok = false;
        if (x != 0u && x != 0x3F800000u) f32ok = false;
        uint32_t lo = x & 0xFFFFu, hi = x >> 16;
        if (!((lo == 0u || lo == 0x3F80u) && (hi == 0u || hi == 0x3F80u))) bfok = false;
    }
    ml = i32ok ? 1 : (f32ok ? 3 : (bfok ? 2 : 0));
}

// ---- K1 (grid 513): blocks 0..511: tn = obj @ w_node^T (tiled f32 SGEMM, NT,
//      raw inputs, XCD-aware bm-fastest mapping) + single-writer s1/s2 slots
//      + 16 CNT ints zeroed per block + gid0 publishes flags.
//      Block 512: reduced v_edge ONLY (4 waves x 64 coalesced float4 steps). ----
__global__ __launch_bounds__(256) void k_nodefc(const void* obj, const void* wn,
                                                const void* we, const void* wa,
                                                const void* emask, float* ws) {
    int isBF, ml;
    detect(obj, emask, isBF, ml);
    int t = threadIdx.x;
    if (blockIdx.x == 0 && t == 0) { ((int*)ws)[0] = isBF; ((int*)ws)[1] = ml; }
    if (blockIdx.x == 512) {
        // v_edge[k] = sum_d wa3[d] * w_edge[d][k]; wave w covers d in [64w,64w+64)
        __shared__ float vep[4][D_];
        int w = t >> 6, lane = t & 63;
        int d0 = w * 64;
        float4 a = make_float4(0.f, 0.f, 0.f, 0.f);
        #pragma unroll 8
        for (int i = 0; i < 64; ++i) {
            int d = d0 + i;
            float c = loadF(wa, 513 + d, isBF);             // uniform
            float4 v = loadF4(we, d * D_ + lane * 4, isBF); // coalesced 1KB/wave
            a.x += c * v.x; a.y += c * v.y; a.z += c * v.z; a.w += c * v.w;
        }
        *(float4*)&vep[w][lane * 4] = a;
        __syncthreads();
        ws[OFF_VE + t] = vep[0][t] + vep[1][t] + vep[2][t] + vep[3][t];
        return;
    }
    __shared__ float As[32][68];
    __shared__ float Bs[32][68];
    float* tn = ws + OFF_TN;
    // zero bucket counters: 8192 ints / 512 blocks = 16 per block (plain stores)
    if (t < 16) ((int*)ws)[OFF_CNT + blockIdx.x * 16 + t] = 0;
    int tx = t & 15, ty = t >> 4;
    int bm = blockIdx.x & 127, bn = blockIdx.x >> 7;   // bm fastest (XCD locality)
    int row0 = bm * 64, col0 = bn * 64;
    int sr = t >> 2;
    int sk = (t & 3) * 8;
    float acc[4][4] = {};
    for (int kt = 0; kt < 8; ++kt) {
        int k0 = kt * 32;
        __syncthreads();
        float4 a0 = loadF4(obj, (row0 + sr) * D_ + k0 + sk, isBF);
        float4 a1 = loadF4(obj, (row0 + sr) * D_ + k0 + sk + 4, isBF);
        float4 b0 = loadF4(wn, (col0 + sr) * D_ + k0 + sk, isBF);
        float4 b1 = loadF4(wn, (col0 + sr) * D_ + k0 + sk + 4, isBF);
        As[sk+0][sr] = a0.x; As[sk+1][sr] = a0.y; As[sk+2][sr] = a0.z; As[sk+3][sr] = a0.w;
        As[sk+4][sr] = a1.x; As[sk+5][sr] = a1.y; As[sk+6][sr] = a1.z; As[sk+7][sr] = a1.w;
        Bs[sk+0][sr] = b0.x; Bs[sk+1][sr] = b0.y; Bs[sk+2][sr] = b0.z; Bs[sk+3][sr] = b0.w;
        Bs[sk+4][sr] = b1.x; Bs[sk+5][sr] = b1.y; Bs[sk+6][sr] = b1.z; Bs[sk+7][sr] = b1.w;
        __syncthreads();
        #pragma unroll
        for (int k = 0; k < 32; ++k) {
            float4 av = *(const float4*)&As[k][ty * 4];
            float4 bv = *(const float4*)&Bs[k][tx * 4];
            acc[0][0] += av.x * bv.x; acc[0][1] += av.x * bv.y;
            acc[0][2] += av.x * bv.z; acc[0][3] += av.x * bv.w;
            acc[1][0] += av.y * bv.x; acc[1][1] += av.y * bv.y;
            acc[1][2] += av.y * bv.z; acc[1][3] += av.y * bv.w;
            acc[2][0] += av.z * bv.x; acc[2][1] += av.z * bv.y;
            acc[2][2] += av.z * bv.z; acc[2][3] += av.z * bv.w;
            acc[3][0] += av.w * bv.x; acc[3][1] += av.w * bv.y;
            acc[3][2] += av.w * bv.z; acc[3][3] += av.w * bv.w;
        }
    }
    #pragma unroll
    for (int rr = 0; rr < 4; ++rr) {
        float4 o = make_float4(acc[rr][0], acc[rr][1], acc[rr][2], acc[rr][3]);
        *(float4*)&tn[(size_t)(row0 + ty * 4 + rr) * D_ + col0 + tx * 4] = o;
    }
    // s1/s2 partial dots over this block's 64 cols -> single-writer slot [bn][row]
    float w1v[4], w2v[4];
    #pragma unroll
    for (int c = 0; c < 4; ++c) {
        w1v[c] = loadF(wa, col0 + tx * 4 + c, isBF);
        w2v[c] = loadF(wa, D_ + col0 + tx * 4 + c, isBF);
    }
    #pragma unroll
    for (int rr = 0; rr < 4; ++rr) {
        float p1 = acc[rr][0]*w1v[0] + acc[rr][1]*w1v[1] + acc[rr][2]*w1v[2] + acc[rr][3]*w1v[3];
        float p2 = acc[rr][0]*w2v[0] + acc[rr][1]*w2v[1] + acc[rr][2]*w2v[2] + acc[rr][3]*w2v[3];
        #pragma unroll
        for (int o = 1; o < 16; o <<= 1) {
            p1 += __shfl_xor(p1, o);
            p2 += __shfl_xor(p2, o);
        }
        if (tx == 0) {
            ws[OFF_S1P + bn * NBUCKET + row0 + ty * 4 + rr] = p1;
            ws[OFF_S2P + bn * NBUCKET + row0 + ty * 4 + rr] = p2;
        }
    }
}

// ---- K2: edge scores, wave per edge; flags from ws (2 int loads — NOT inline
//          detect; that cost ~150us in this 131K-wave kernel, R13/R16);
//          mask-skip; reduced-VE read; s1/s2 4-slot sums on lane 0; bucket fill. ----
__global__ __launch_bounds__(256) void k_scores(const void* pred, const int2* rel,
                                                const void* emask, const void* sim,
                                                const void* wa, float* ws) {
    const int* flags = (const int*)ws;
    int isBF = flags[0], ml = flags[1];
    int gid = blockIdx.x * blockDim.x + threadIdx.x;
    int gw = gid >> 6, lane = gid & 63;
    if (gw >= B_ * E_) return;
    bool m = readMask(emask, gw, ml);      // wave-uniform
    if (!m) {
        if (lane == 0) ws[OFF_SC + gw] = -1e9f;
        return;
    }
    int b = gw >> 13;
    float4 ve4 = *(const float4*)(ws + OFF_VE + lane * 4);   // reduced, L1-hot
    float dot;
    if (isBF) {
        ushort4 v = *(const ushort4*)((const uint16_t*)pred + (size_t)gw * D_ + lane * 4);
        dot = bf2f(v.x)*ve4.x + bf2f(v.y)*ve4.y + bf2f(v.z)*ve4.z + bf2f(v.w)*ve4.w;
    } else {
        float4 v = *(const float4*)((const float*)pred + (size_t)gw * D_ + lane * 4);
        dot = v.x*ve4.x + v.y*ve4.y + v.z*ve4.z + v.w*ve4.w;
    }
    #pragma unroll
    for (int off = 32; off > 0; off >>= 1) dot += __shfl_xor(dot, off);
    if (lane == 0) {
        int2 sd = rel[gw];
        int rx = b * N_ + sd.x, ry = b * N_ + sd.y;
        float s1 = ws[OFF_S1P + rx] + ws[OFF_S1P + NBUCKET + rx]
                 + ws[OFF_S1P + 2*NBUCKET + rx] + ws[OFF_S1P + 3*NBUCKET + rx];
        float s2 = ws[OFF_S2P + ry] + ws[OFF_S2P + NBUCKET + ry]
                 + ws[OFF_S2P + 2*NBUCKET + ry] + ws[OFF_S2P + 3*NBUCKET + ry];
        float s = dot + s1 + s2 + loadF(sim, gw, isBF) * loadF(wa, 512, isBF);
        s = (s > 0.f) ? s : 0.01f * s;                 // leaky_relu
        ws[OFF_SC + gw] = s;
        int slot = atomicAdd((int*)ws + OFF_CNT + ry, 1);
        if (slot < CAP)
            ((int*)ws)[OFF_REC + ry * CAP + slot] = sd.x | ((gw & (E_ - 1)) << 16);
    }
}

// ---- K3: block = 4 nodes of one batch; batch XCD-pinned (b = blk & 15).
//          Flags from ws. In-block softmax stats from L2-hot SC, then
//          wave-per-node register accum + node-mask + LayerNorm. ----
__global__ __launch_bounds__(256) void k_scatter_ln(const void* nmask, const void* gam,
                                                    const void* bet, const float* wsc,
                                                    void* out) {
    __shared__ float red[4];
    const float* ws = wsc;
    const int* flags = (const int*)ws;
    int isBF = flags[0], ml = flags[1];
    int t = threadIdx.x, w = t >> 6, lane = t & 63;
    int b  = blockIdx.x & 15;              // batch (XCD-pinned)
    int s4 = (blockIdx.x >> 4) * 4;        // first node of this block's group
    int ng = b * N_ + s4 + w;              // (batch,node), 0..8191
    const float* sc = ws + OFF_SC + b * E_;
    // in-block softmax stats over this batch's 8192 scores (32 KB, L2-hot)
    float loc[8][4];
    float mx = -3e38f;
    #pragma unroll
    for (int k = 0; k < 8; ++k) {
        float4 v = *(const float4*)(sc + t * 4 + k * 1024);
        loc[k][0] = v.x; loc[k][1] = v.y; loc[k][2] = v.z; loc[k][3] = v.w;
        mx = fmaxf(mx, fmaxf(fmaxf(v.x, v.y), fmaxf(v.z, v.w)));
    }
    #pragma unroll
    for (int o = 32; o > 0; o >>= 1) mx = fmaxf(mx, __shfl_xor(mx, o));
    if (lane == 0) red[w] = mx;
    __syncthreads();
    float M = fmaxf(fmaxf(red[0], red[1]), fmaxf(red[2], red[3]));
    float sum = 0.f;
    #pragma unroll
    for (int k = 0; k < 8; ++k)
        sum += __expf(loc[k][0] - M) + __expf(loc[k][1] - M)
             + __expf(loc[k][2] - M) + __expf(loc[k][3] - M);
    #pragma unroll
    for (int o = 32; o > 0; o >>= 1) sum += __shfl_xor(sum, o);
    __syncthreads();
    if (lane == 0) red[w] = sum;
    __syncthreads();
    float invS = 1.f / (red[0] + red[1] + red[2] + red[3]);
    // wave-per-node gather/accumulate
    int cnt = ((const int*)ws)[OFF_CNT + ng];
    if (cnt > CAP) cnt = CAP;
    const int* rec = (const int*)ws + OFF_REC + ng * CAP;
    const float* tn = ws + OFF_TN + (size_t)b * N_ * D_;
    float v0 = 0.f, v1 = 0.f, v2 = 0.f, v3 = 0.f;
    for (int i = 0; i < cnt; ++i) {
        int rc = rec[i];
        int src = rc & 0xFFFF;
        float wv = __expf(sc[((unsigned)rc) >> 16] - M) * invS;
        const float* s = tn + (size_t)src * D_;
        v0 += wv * s[lane];
        v1 += wv * s[lane + 64];
        v2 += wv * s[lane + 128];
        v3 += wv * s[lane + 192];
    }
    float mk = readMask(nmask, ng, ml) ? 1.f : 0.f;
    v0 *= mk; v1 *= mk; v2 *= mk; v3 *= mk;
    float s_ = v0 + v1 + v2 + v3;
    float sq = v0*v0 + v1*v1 + v2*v2 + v3*v3;
    #pragma unroll
    for (int o = 32; o > 0; o >>= 1) {
        s_ += __shfl_xor(s_, o);
        sq += __shfl_xor(sq, o);
    }
    float mu  = s_ * (1.f / 256.f);
    float var = fmaxf(sq * (1.f / 256.f) - mu * mu, 0.f);
    float rs  = rsqrtf(var + 1e-5f);
    size_t ro = (size_t)ng * D_;
    float g0 = loadF(gam, lane,       isBF), c0 = loadF(bet, lane,       isBF);
    float g1 = loadF(gam, lane + 64,  isBF), c1 = loadF(bet, lane + 64,  isBF);
    float g2 = loadF(gam, lane + 128, isBF), c2 = loadF(bet, lane + 128, isBF);
    float g3 = loadF(gam, lane + 192, isBF), c3 = loadF(bet, lane + 192, isBF);
    float r0 = (v0 - mu) * rs * g0 + c0;
    float r1 = (v1 - mu) * rs * g1 + c1;
    float r2 = (v2 - mu) * rs * g2 + c2;
    float r3 = (v3 - mu) * rs * g3 + c3;
    if (isBF) {
        __hip_bfloat16* o = (__hip_bfloat16*)out + ro;
        o[lane]       = __float2bfloat16(r0);
        o[lane + 64]  = __float2bfloat16(r1);
        o[lane + 128] = __float2bfloat16(r2);
        o[lane + 192] = __float2bfloat16(r3);
    } else {
        float* o = (float*)out + ro;
        o[lane] = r0; o[lane + 64] = r1; o[lane + 128] = r2; o[lane + 192] = r3;
    }
}

extern "C" void kernel_launch(void* const* d_in, const int* in_sizes, int n_in,
                              void* d_out, int out_size, void* d_ws, size_t ws_size,
                              hipStream_t stream) {
    (void)in_sizes; (void)n_in; (void)out_size; (void)ws_size;
    const void* obj   = d_in[0];
    const void* pred  = d_in[1];
    const int2* rel   = (const int2*)d_in[2];
    const void* sim   = d_in[3];
    const void* nmask = d_in[4];
    const void* emask = d_in[5];
    const void* wn    = d_in[6];
    const void* we    = d_in[7];
    const void* wa    = d_in[8];
    const void* gam   = d_in[9];
    const void* bet   = d_in[10];
    float* ws = (float*)d_ws;

    k_nodefc<<<513, 256, 0, stream>>>(obj, wn, we, wa, emask, ws);
    k_scores<<<(B_ * E_) / 4, 256, 0, stream>>>(pred, rel, emask, sim, wa, ws);
    k_scatter_ln<<<NBUCKET / 4, 256, 0, stream>>>(nmask, gam, bet, ws, d_out);
}